// Round 3
// baseline (2452.417 us; speedup 1.0000x reference)
//
#include <hip/hip_runtime.h>

#define T_STEPS 200
#define BATCH   32
#define HID     1024
#define NWG     256
#define NTHR    512

typedef _Float16 half8 __attribute__((ext_vector_type(8)));
typedef float    f32x4 __attribute__((ext_vector_type(4)));

struct Bar {
    unsigned flag[NWG * 32];   // one 128B line per WG (arrival tick, RMW-free)
    unsigned gen[8 * 32];      // 8 broadcast lines (released tick)
};

// Coherent (agent-scope, cache-bypassing) 16B load/store from two relaxed 8B
// atomics. Used ONLY for cross-WG data (h ping-pong, y0m). No fences -> no
// buffer_inv / buffer_wbl2 anywhere.
__device__ __forceinline__ half8 ld_coh16(const _Float16* p) {
    union { unsigned long long u[2]; half8 h; } r;
    const unsigned long long* q = (const unsigned long long*)p;
    r.u[0] = __hip_atomic_load(q,     __ATOMIC_RELAXED, __HIP_MEMORY_SCOPE_AGENT);
    r.u[1] = __hip_atomic_load(q + 1, __ATOMIC_RELAXED, __HIP_MEMORY_SCOPE_AGENT);
    return r.h;
}
__device__ __forceinline__ void st_coh16(_Float16* p, half8 v) {
    union { half8 h; unsigned long long u[2]; } r; r.h = v;
    unsigned long long* q = (unsigned long long*)p;
    __hip_atomic_store(q,     r.u[0], __ATOMIC_RELAXED, __HIP_MEMORY_SCOPE_AGENT);
    __hip_atomic_store(q + 1, r.u[1], __ATOMIC_RELAXED, __HIP_MEMORY_SCOPE_AGENT);
}

__device__ __forceinline__ half8 cvt8(const float* p) {
    f32x4 lo = *(const f32x4*)p;
    f32x4 hi = *(const f32x4*)(p + 4);
    half8 a;
    a[0] = (_Float16)lo[0]; a[1] = (_Float16)lo[1];
    a[2] = (_Float16)lo[2]; a[3] = (_Float16)lo[3];
    a[4] = (_Float16)hi[0]; a[5] = (_Float16)hi[1];
    a[6] = (_Float16)hi[2]; a[7] = (_Float16)hi[3];
    return a;
}

__global__ void init_k(const float* __restrict__ h0,
                       _Float16* __restrict__ h0b, _Float16* __restrict__ h1b,
                       Bar* __restrict__ bar) {
    int i = blockIdx.x * blockDim.x + threadIdx.x;
    if (i < BATCH * HID) {
        h0b[i] = (_Float16)h0[i];                 // layer 0 initial h -> buf 0
        h1b[i] = (_Float16)h0[BATCH * HID + i];   // layer 1 initial h -> buf 0
    }
    if (blockIdx.x == 0) {
        if (threadIdx.x < NWG) bar->flag[threadIdx.x * 32] = 0;
        if (threadIdx.x < 8)   bar->gen[threadIdx.x * 32]  = 0;
    }
}

// 256 WGs x 512 threads. WGs 0-127: layer 0 (t = tick). WGs 128-255: layer 1
// (t = tick-1, wavefront pipeline). Weights persist in LDS (f16, XOR-swizzle).
// Cross-WG traffic (h ping-pong, y0m) via relaxed agent-scope atomics (LLC).
// Barrier: per-WG flag lines (parallel stores) -> WG0 polls all 256 flags
// (256 threads) -> publishes gen to 8 lines -> WGs spin on gen[bid&7].
// No atomic RMW anywhere on the tick path.
__global__ __launch_bounds__(NTHR, 2) void lstm_main(
    const float* __restrict__ x, const float* __restrict__ c0,
    const float* __restrict__ Wih, const float* __restrict__ Whh,
    const float* __restrict__ bih, const float* __restrict__ bhh,
    const float* __restrict__ mi, const float* __restrict__ mo,
    float* __restrict__ out,
    _Float16* __restrict__ y0m, _Float16* __restrict__ h0b,
    _Float16* __restrict__ h1b, Bar* __restrict__ bar)
{
    __shared__ _Float16 W_s[32 * 2048];     // 128 KB
    __shared__ float scr[8][2][16][17];     // per-wave partial gate tiles (+pad)
    __shared__ float c_s[BATCH][8];         // persistent cell state (f32)
    __shared__ alignas(16) _Float16 st_h[BATCH][8];  // staged h for wave-0 stores
    __shared__ alignas(16) _Float16 st_y[BATCH][8];  // staged y0*mask (layer 0)

    const int bid   = blockIdx.x;
    const int layer = bid >> 7;
    const int wgl   = bid & 127;
    const int tid   = threadIdx.x;

    // ---- one-time: stage this WG's weight slice into LDS (f16, swizzled) ----
    const float* WihL = Wih + (size_t)layer * 4 * HID * HID;
    const float* WhhL = Whh + (size_t)layer * 4 * HID * HID;
    for (int idx = tid; idx < 32 * 2048; idx += NTHR) {
        int r = idx >> 11, k = idx & 2047;             // r: local gate-row, k: 0..2047
        int grow = (r >> 3) * HID + wgl * 8 + (r & 7); // global row in [4H]
        float v = (k < HID) ? WihL[(size_t)grow * HID + k]
                            : WhhL[(size_t)grow * HID + (k - HID)];
        W_s[idx ^ ((r & 7) << 3)] = (_Float16)v;       // XOR-swizzle (16B granules)
    }

    float bias0 = 0.f, bias1 = 0.f, bias2 = 0.f, bias3 = 0.f;
    int b_ = 0, col_ = 0, gcol = 0;
    if (tid < 256) {
        b_ = tid >> 3; col_ = tid & 7; gcol = wgl * 8 + col_;
        bias0 = bih[layer * 4096 + gcol]           + bhh[layer * 4096 + gcol];
        bias1 = bih[layer * 4096 + HID + gcol]     + bhh[layer * 4096 + HID + gcol];
        bias2 = bih[layer * 4096 + 2 * HID + gcol] + bhh[layer * 4096 + 2 * HID + gcol];
        bias3 = bih[layer * 4096 + 3 * HID + gcol] + bhh[layer * 4096 + 3 * HID + gcol];
        c_s[b_][col_] = c0[((size_t)layer * BATCH + b_) * HID + gcol];
    }
    __syncthreads();

    const int lane = tid & 63, wid = tid >> 6;
    const int m  = wid & 1;          // M-tile (batch 0-15 / 16-31)
    const int kq = wid >> 1;         // K quarter (512 each)
    const int row = lane & 15, bb = m * 16 + row, ko = (lane >> 4) * 8;
    const int grp = bid & 7;

    // ---- prefetched pure-t inputs for the upcoming tick ----
    half8 aF[16];
    float mi_reg = 0.f, mo_reg = 0.f;
    if (layer == 0) {
        if (kq < 2) {
            const float* xp = x + (size_t)bb * HID + kq * 512 + ko;   // t = 0
            #pragma unroll
            for (int kk = 0; kk < 16; ++kk) aF[kk] = cvt8(xp + kk * 32);
        }
        if (tid < 256) mi_reg = mi[(size_t)b_ * HID + gcol];          // t = 0
    }

    for (int tk = 0; tk <= T_STEPS; ++tk) {
        const bool active = (layer == 0) ? (tk < T_STEPS) : (tk >= 1);
        if (active) {
            const int t = (layer == 0) ? tk : tk - 1;
            // ---- barrier-dependent A fragments ----
            if (layer == 0) {
                if (kq >= 2) {
                    const _Float16* hp = h0b + (tk & 1) * (BATCH * HID)
                                       + bb * HID + (kq - 2) * 512 + ko;
                    #pragma unroll
                    for (int kk = 0; kk < 16; ++kk) aF[kk] = ld_coh16(hp + kk * 32);
                }
            } else {
                if (kq < 2) {
                    const _Float16* yp = y0m + ((size_t)t * BATCH + bb) * HID + kq * 512 + ko;
                    #pragma unroll
                    for (int kk = 0; kk < 16; ++kk) aF[kk] = ld_coh16(yp + kk * 32);
                } else {
                    const _Float16* hp = h1b + (((tk + 1) & 1)) * (BATCH * HID)
                                       + bb * HID + (kq - 2) * 512 + ko;
                    #pragma unroll
                    for (int kk = 0; kk < 16; ++kk) aF[kk] = ld_coh16(hp + kk * 32);
                }
            }

            f32x4 acc0 = {0.f, 0.f, 0.f, 0.f}, acc1 = {0.f, 0.f, 0.f, 0.f};
            #pragma unroll
            for (int kk = 0; kk < 16; ++kk) {
                const int k  = kq * 512 + kk * 32 + ko;
                const int r1 = 16 + row;
                const half8 b0 = *(const half8*)&W_s[(row * 2048 + k) ^ ((row & 7) << 3)];
                const half8 b1 = *(const half8*)&W_s[(r1 * 2048 + k) ^ ((r1 & 7) << 3)];
                acc0 = __builtin_amdgcn_mfma_f32_16x16x32_f16(aF[kk], b0, acc0, 0, 0, 0);
                acc1 = __builtin_amdgcn_mfma_f32_16x16x32_f16(aF[kk], b1, acc1, 0, 0, 0);
            }
            #pragma unroll
            for (int j = 0; j < 4; ++j) {
                scr[wid][0][(lane >> 4) * 4 + j][row] = acc0[j];
                scr[wid][1][(lane >> 4) * 4 + j][row] = acc1[j];
            }
            __syncthreads();

            // ---- activations: thread owns (batch b_, hidden col gcol) ----
            if (tid < 256) {
                const int m2 = b_ >> 4, rD = b_ & 15;
                float v0 = 0.f, v1 = 0.f, v2 = 0.f, v3 = 0.f;
                #pragma unroll
                for (int q = 0; q < 4; ++q) {
                    v0 += scr[q * 2 + m2][0][rD][col_];       // gate i
                    v1 += scr[q * 2 + m2][0][rD][8 + col_];   // gate f
                    v2 += scr[q * 2 + m2][1][rD][col_];       // gate g
                    v3 += scr[q * 2 + m2][1][rD][8 + col_];   // gate o
                }
                const float ig = 1.f / (1.f + __expf(-(v0 + bias0)));
                const float fg = 1.f / (1.f + __expf(-(v1 + bias1)));
                const float gg = tanhf(v2 + bias2);
                const float og = 1.f / (1.f + __expf(-(v3 + bias3)));
                const float cc = fg * c_s[b_][col_] + ig * gg;
                const float hh = og * tanhf(cc);
                c_s[b_][col_] = cc;

                st_h[b_][col_] = (_Float16)hh;

                const size_t oidx = ((size_t)t * BATCH + b_) * HID + gcol;
                if (layer == 0) {
                    st_y[b_][col_] = (_Float16)(hh * mi_reg);
                } else {
                    out[oidx] = hh * mo_reg;
                }
                if (t == T_STEPS - 1) {
                    const size_t base = (size_t)T_STEPS * BATCH * HID;
                    out[base + ((size_t)layer * BATCH + b_) * HID + gcol] = hh;
                    out[base + (size_t)2 * BATCH * HID + ((size_t)layer * BATCH + b_) * HID + gcol] = cc;
                }
            }
            __syncthreads();

            // ---- wave 0 funnels ALL cross-WG stores (covered by one vmcnt) ----
            if (tid < BATCH) {
                _Float16* hwr = (layer == 0) ? (h0b + (((tk + 1) & 1)) * (BATCH * HID))
                                             : (h1b + ((tk & 1)) * (BATCH * HID));
                st_coh16(&hwr[tid * HID + wgl * 8], *(const half8*)st_h[tid]);
                if (layer == 0)
                    st_coh16(&y0m[((size_t)t * BATCH + tid) * HID + wgl * 8],
                             *(const half8*)st_y[tid]);
            }
        }

        if (tk == T_STEPS) break;   // last tick needs no barrier

        const unsigned tgt = (unsigned)(tk + 1);

        // ---- arrive: wave 0 waits its coherent stores, then flags own line ----
        if (tid == 0) {
            asm volatile("s_waitcnt vmcnt(0)" ::: "memory");
            __hip_atomic_store(&bar->flag[bid * 32], tgt,
                               __ATOMIC_RELAXED, __HIP_MEMORY_SCOPE_AGENT);
        }

        // ---- prefetch next tick's pure-t inputs while the barrier settles ----
        if (layer == 0) {
            if (kq < 2 && tk + 1 < T_STEPS) {
                const float* xp = x + ((size_t)(tk + 1) * BATCH + bb) * HID + kq * 512 + ko;
                #pragma unroll
                for (int kk = 0; kk < 16; ++kk) aF[kk] = cvt8(xp + kk * 32);
            }
            if (tid < 256 && tk + 1 < T_STEPS)
                mi_reg = mi[((size_t)(tk + 1) * BATCH + b_) * HID + gcol];
        } else {
            if (tid < 256 && tk < T_STEPS)
                mo_reg = mo[((size_t)tk * BATCH + b_) * HID + gcol];
        }

        // ---- wait ----
        if (bid == 0) {
            if (tid < NWG) {
                while (__hip_atomic_load(&bar->flag[tid * 32], __ATOMIC_RELAXED,
                                         __HIP_MEMORY_SCOPE_AGENT) < tgt)
                    __builtin_amdgcn_s_sleep(1);
            }
            __syncthreads();
            if (tid < 8)
                __hip_atomic_store(&bar->gen[tid * 32], tgt,
                                   __ATOMIC_RELAXED, __HIP_MEMORY_SCOPE_AGENT);
        } else {
            if (tid == 0) {
                while (__hip_atomic_load(&bar->gen[grp * 32], __ATOMIC_RELAXED,
                                         __HIP_MEMORY_SCOPE_AGENT) < tgt)
                    __builtin_amdgcn_s_sleep(1);
            }
        }
        asm volatile("" ::: "memory");   // no code motion across the spin
        __syncthreads();
    }
}

extern "C" void kernel_launch(void* const* d_in, const int* in_sizes, int n_in,
                              void* d_out, int out_size, void* d_ws, size_t ws_size,
                              hipStream_t stream) {
    const float* x   = (const float*)d_in[0];
    const float* h0  = (const float*)d_in[1];
    const float* c0  = (const float*)d_in[2];
    const float* Wih = (const float*)d_in[3];
    const float* Whh = (const float*)d_in[4];
    const float* bih = (const float*)d_in[5];
    const float* bhh = (const float*)d_in[6];
    const float* mi  = (const float*)d_in[7];
    const float* mo  = (const float*)d_in[8];
    float* out = (float*)d_out;

    char* w = (char*)d_ws;
    _Float16* y0m = (_Float16*)w;                                  // 13,107,200 B
    _Float16* h0b = (_Float16*)(w + 13107200);                     //   131,072 B (2 bufs)
    _Float16* h1b = (_Float16*)(w + 13107200 + 131072);            //   131,072 B
    Bar*      bar = (Bar*)(w + 13107200 + 262144);

    hipLaunchKernelGGL(init_k, dim3(128), dim3(256), 0, stream, h0, h0b, h1b, bar);

    void* args[] = {(void*)&x, (void*)&c0, (void*)&Wih, (void*)&Whh,
                    (void*)&bih, (void*)&bhh, (void*)&mi, (void*)&mo,
                    (void*)&out, (void*)&y0m, (void*)&h0b, (void*)&h1b, (void*)&bar};
    hipLaunchCooperativeKernel((void*)lstm_main, dim3(NWG), dim3(NTHR),
                               args, 0, stream);
}

// Round 4
// 2176.977 us; speedup vs baseline: 1.1265x; 1.1265x over previous
//
#include <hip/hip_runtime.h>

#define T_STEPS 200
#define BATCH   32
#define HID     1024
#define NWG     256
#define NTHR    512

typedef _Float16 half8 __attribute__((ext_vector_type(8)));
typedef float    f32x4 __attribute__((ext_vector_type(4)));

struct Bar {
    unsigned cnt[2][8 * 32];   // [parity][group] arrival counters (one line each)
    unsigned gcnt[2 * 32];     // [parity] group-of-groups counter
    unsigned gen[8 * 32];      // 8 broadcast lines (released tick, monotonic)
};

// Coherent (agent-scope, cache-bypassing) 16B load/store from two relaxed 8B
// atomics. Used ONLY for cross-WG data (h ping-pong, y0m). No fences -> no
// buffer_inv / buffer_wbl2 anywhere.
__device__ __forceinline__ half8 ld_coh16(const _Float16* p) {
    union { unsigned long long u[2]; half8 h; } r;
    const unsigned long long* q = (const unsigned long long*)p;
    r.u[0] = __hip_atomic_load(q,     __ATOMIC_RELAXED, __HIP_MEMORY_SCOPE_AGENT);
    r.u[1] = __hip_atomic_load(q + 1, __ATOMIC_RELAXED, __HIP_MEMORY_SCOPE_AGENT);
    return r.h;
}
__device__ __forceinline__ void st_coh16(_Float16* p, half8 v) {
    union { half8 h; unsigned long long u[2]; } r; r.h = v;
    unsigned long long* q = (unsigned long long*)p;
    __hip_atomic_store(q,     r.u[0], __ATOMIC_RELAXED, __HIP_MEMORY_SCOPE_AGENT);
    __hip_atomic_store(q + 1, r.u[1], __ATOMIC_RELAXED, __HIP_MEMORY_SCOPE_AGENT);
}

__device__ __forceinline__ half8 cvt8(const float* p) {
    f32x4 lo = *(const f32x4*)p;
    f32x4 hi = *(const f32x4*)(p + 4);
    half8 a;
    a[0] = (_Float16)lo[0]; a[1] = (_Float16)lo[1];
    a[2] = (_Float16)lo[2]; a[3] = (_Float16)lo[3];
    a[4] = (_Float16)hi[0]; a[5] = (_Float16)hi[1];
    a[6] = (_Float16)hi[2]; a[7] = (_Float16)hi[3];
    return a;
}

__global__ void init_k(const float* __restrict__ h0,
                       _Float16* __restrict__ h0b, _Float16* __restrict__ h1b,
                       Bar* __restrict__ bar) {
    int i = blockIdx.x * blockDim.x + threadIdx.x;
    if (i < BATCH * HID) {
        h0b[i] = (_Float16)h0[i];                 // layer 0 initial h -> buf 0
        h1b[i] = (_Float16)h0[BATCH * HID + i];   // layer 1 initial h -> buf 0
    }
    if (blockIdx.x == 0) {
        if (threadIdx.x < 8) {
            bar->cnt[0][threadIdx.x * 32] = 0;
            bar->cnt[1][threadIdx.x * 32] = 0;
            bar->gen[threadIdx.x * 32]    = 0;
        }
        if (threadIdx.x < 2) bar->gcnt[threadIdx.x * 32] = 0;
    }
}

// 256 WGs x 512 threads. WGs 0-127: layer 0 (t = tick). WGs 128-255: layer 1
// (t = tick-1, wavefront pipeline). Weights persist in LDS (f16, XOR-swizzle).
// Cross-WG traffic (h ping-pong, y0m) via relaxed agent-scope atomics (LLC).
// Barrier = R2's pipelined-RMW arrive + push release, with parity counters
// (reset off critical path), lane-parallel gen publish, and BUSY waits
// (junk v_fma, no s_sleep) to keep the clock governor from downclocking.
__global__ __launch_bounds__(NTHR, 2) void lstm_main(
    const float* __restrict__ x, const float* __restrict__ c0,
    const float* __restrict__ Wih, const float* __restrict__ Whh,
    const float* __restrict__ bih, const float* __restrict__ bhh,
    const float* __restrict__ mi, const float* __restrict__ mo,
    float* __restrict__ out,
    _Float16* __restrict__ y0m, _Float16* __restrict__ h0b,
    _Float16* __restrict__ h1b, Bar* __restrict__ bar)
{
    __shared__ _Float16 W_s[32 * 2048];     // 128 KB
    __shared__ float scr[8][2][16][17];     // per-wave partial gate tiles (+pad)
    __shared__ float c_s[BATCH][8];         // persistent cell state (f32)
    __shared__ alignas(16) _Float16 st_h[BATCH][8];  // staged h for wave-0 stores
    __shared__ alignas(16) _Float16 st_y[BATCH][8];  // staged y0*mask (layer 0)
    __shared__ unsigned rel_flag;           // intra-WG release (LDS)

    const int bid   = blockIdx.x;
    const int layer = bid >> 7;
    const int wgl   = bid & 127;
    const int tid   = threadIdx.x;

    if (tid == 0) rel_flag = 0;

    // ---- one-time: stage this WG's weight slice into LDS (f16, swizzled) ----
    const float* WihL = Wih + (size_t)layer * 4 * HID * HID;
    const float* WhhL = Whh + (size_t)layer * 4 * HID * HID;
    for (int idx = tid; idx < 32 * 2048; idx += NTHR) {
        int r = idx >> 11, k = idx & 2047;             // r: local gate-row, k: 0..2047
        int grow = (r >> 3) * HID + wgl * 8 + (r & 7); // global row in [4H]
        float v = (k < HID) ? WihL[(size_t)grow * HID + k]
                            : WhhL[(size_t)grow * HID + (k - HID)];
        W_s[idx ^ ((r & 7) << 3)] = (_Float16)v;       // XOR-swizzle (16B granules)
    }

    float bias0 = 0.f, bias1 = 0.f, bias2 = 0.f, bias3 = 0.f;
    int b_ = 0, col_ = 0, gcol = 0;
    if (tid < 256) {
        b_ = tid >> 3; col_ = tid & 7; gcol = wgl * 8 + col_;
        bias0 = bih[layer * 4096 + gcol]           + bhh[layer * 4096 + gcol];
        bias1 = bih[layer * 4096 + HID + gcol]     + bhh[layer * 4096 + HID + gcol];
        bias2 = bih[layer * 4096 + 2 * HID + gcol] + bhh[layer * 4096 + 2 * HID + gcol];
        bias3 = bih[layer * 4096 + 3 * HID + gcol] + bhh[layer * 4096 + 3 * HID + gcol];
        c_s[b_][col_] = c0[((size_t)layer * BATCH + b_) * HID + gcol];
    }
    __syncthreads();

    const int lane = tid & 63, wid = tid >> 6;
    const int m  = wid & 1;          // M-tile (batch 0-15 / 16-31)
    const int kq = wid >> 1;         // K quarter (512 each)
    const int row = lane & 15, bb = m * 16 + row, ko = (lane >> 4) * 8;
    const int grp = bid & 7;

    for (int tk = 0; tk <= T_STEPS; ++tk) {
        const bool active = (layer == 0) ? (tk < T_STEPS) : (tk >= 1);
        if (active) {
            const int t = (layer == 0) ? tk : tk - 1;
            const _Float16* hrd = (layer == 0) ? (h0b + (tk & 1) * (BATCH * HID))
                                               : (h1b + (((tk + 1) & 1)) * (BATCH * HID));
            f32x4 acc0 = {0.f, 0.f, 0.f, 0.f}, acc1 = {0.f, 0.f, 0.f, 0.f};

            // ---- A fragments: [x_t | h] row bb, K quarter kq ----
            half8 aF[16];
            if (kq < 2) {
                if (layer == 0) {
                    const float* xp = x + ((size_t)t * BATCH + bb) * HID + kq * 512 + ko;
                    #pragma unroll
                    for (int kk = 0; kk < 16; ++kk) aF[kk] = cvt8(xp + kk * 32);
                } else {
                    const _Float16* yp = y0m + ((size_t)t * BATCH + bb) * HID + kq * 512 + ko;
                    #pragma unroll
                    for (int kk = 0; kk < 16; ++kk) aF[kk] = ld_coh16(yp + kk * 32);
                }
            } else {
                const _Float16* hp = hrd + bb * HID + (kq - 2) * 512 + ko;
                #pragma unroll
                for (int kk = 0; kk < 16; ++kk) aF[kk] = ld_coh16(hp + kk * 32);
            }

            // ---- MFMA: D[batch 16][gaterow 16] x2 subtiles over K=512 ----
            #pragma unroll
            for (int kk = 0; kk < 16; ++kk) {
                const int k  = kq * 512 + kk * 32 + ko;
                const int r1 = 16 + row;
                const half8 b0 = *(const half8*)&W_s[(row * 2048 + k) ^ ((row & 7) << 3)];
                const half8 b1 = *(const half8*)&W_s[(r1 * 2048 + k) ^ ((r1 & 7) << 3)];
                acc0 = __builtin_amdgcn_mfma_f32_16x16x32_f16(aF[kk], b0, acc0, 0, 0, 0);
                acc1 = __builtin_amdgcn_mfma_f32_16x16x32_f16(aF[kk], b1, acc1, 0, 0, 0);
            }
            #pragma unroll
            for (int j = 0; j < 4; ++j) {
                scr[wid][0][(lane >> 4) * 4 + j][row] = acc0[j];
                scr[wid][1][(lane >> 4) * 4 + j][row] = acc1[j];
            }
            __syncthreads();

            // ---- activations: thread owns (batch b_, hidden col gcol) ----
            if (tid < 256) {
                const int m2 = b_ >> 4, rD = b_ & 15;
                float v0 = 0.f, v1 = 0.f, v2 = 0.f, v3 = 0.f;
                #pragma unroll
                for (int q = 0; q < 4; ++q) {
                    v0 += scr[q * 2 + m2][0][rD][col_];       // gate i
                    v1 += scr[q * 2 + m2][0][rD][8 + col_];   // gate f
                    v2 += scr[q * 2 + m2][1][rD][col_];       // gate g
                    v3 += scr[q * 2 + m2][1][rD][8 + col_];   // gate o
                }
                const float ig = 1.f / (1.f + __expf(-(v0 + bias0)));
                const float fg = 1.f / (1.f + __expf(-(v1 + bias1)));
                const float gg = tanhf(v2 + bias2);
                const float og = 1.f / (1.f + __expf(-(v3 + bias3)));
                const float cc = fg * c_s[b_][col_] + ig * gg;
                const float hh = og * tanhf(cc);
                c_s[b_][col_] = cc;

                st_h[b_][col_] = (_Float16)hh;

                const size_t oidx = ((size_t)t * BATCH + b_) * HID + gcol;
                if (layer == 0) {
                    st_y[b_][col_] = (_Float16)(hh * mi[oidx]);
                } else {
                    out[oidx] = hh * mo[oidx];
                }
                if (t == T_STEPS - 1) {
                    const size_t base = (size_t)T_STEPS * BATCH * HID;
                    out[base + ((size_t)layer * BATCH + b_) * HID + gcol] = hh;
                    out[base + (size_t)2 * BATCH * HID + ((size_t)layer * BATCH + b_) * HID + gcol] = cc;
                }
            }
            __syncthreads();

            // ---- wave 0 funnels ALL cross-WG stores (covered by one vmcnt) ----
            if (tid < BATCH) {
                _Float16* hwr = (layer == 0) ? (h0b + (((tk + 1) & 1)) * (BATCH * HID))
                                             : (h1b + ((tk & 1)) * (BATCH * HID));
                st_coh16(&hwr[tid * HID + wgl * 8], *(const half8*)st_h[tid]);
                if (layer == 0)
                    st_coh16(&y0m[((size_t)t * BATCH + tid) * HID + wgl * 8],
                             *(const half8*)st_y[tid]);
            }
        }

        if (tk == T_STEPS) break;   // last tick: no barrier needed

        const unsigned tgt = (unsigned)(tk + 1);
        const int p = tk & 1;

        if (wid == 0) {
            // ---- arrive (lane 0): pipelined RMW aggregation, push release ----
            int pubi = 0;
            if (lane == 0) {
                asm volatile("s_waitcnt vmcnt(0)" ::: "memory");
                unsigned old = __hip_atomic_fetch_add(&bar->cnt[p][grp * 32], 1u,
                                   __ATOMIC_RELAXED, __HIP_MEMORY_SCOPE_AGENT);
                if (old == 31u) {
                    unsigned o2 = __hip_atomic_fetch_add(&bar->gcnt[p * 32], 1u,
                                       __ATOMIC_RELAXED, __HIP_MEMORY_SCOPE_AGENT);
                    pubi = (o2 == 7u) ? 1 : 0;
                }
            }
            pubi = __shfl(pubi, 0);
            if (pubi) {
                // lane-parallel publish + off-critical-path parity reset
                if (lane < 8)
                    __hip_atomic_store(&bar->gen[lane * 32], tgt,
                                       __ATOMIC_RELAXED, __HIP_MEMORY_SCOPE_AGENT);
                else if (lane < 16)
                    __hip_atomic_store(&bar->cnt[p][(lane - 8) * 32], 0u,
                                       __ATOMIC_RELAXED, __HIP_MEMORY_SCOPE_AGENT);
                else if (lane == 16)
                    __hip_atomic_store(&bar->gcnt[p * 32], 0u,
                                       __ATOMIC_RELAXED, __HIP_MEMORY_SCOPE_AGENT);
            }
            if (lane == 0) {
                if (!pubi) {
                    float j0 = 0.f, j1 = 0.f;
                    while (__hip_atomic_load(&bar->gen[grp * 32], __ATOMIC_RELAXED,
                                             __HIP_MEMORY_SCOPE_AGENT) < tgt) {
                        asm volatile("v_fma_f32 %0,%0,%0,%0\n"
                                     "v_fma_f32 %1,%1,%1,%1\n"
                                     "v_fma_f32 %0,%0,%0,%0\n"
                                     "v_fma_f32 %1,%1,%1,%1"
                                     : "+v"(j0), "+v"(j1));
                    }
                }
                *(volatile unsigned*)&rel_flag = tgt;
            }
        } else {
            // ---- waves 1-7: busy-wait on LDS flag (keeps SIMDs issuing) ----
            float j0 = 0.f, j1 = 0.f, j2 = 0.f, j3 = 0.f;
            while (*(volatile unsigned*)&rel_flag < tgt) {
                asm volatile("v_fma_f32 %0,%0,%0,%0\n"
                             "v_fma_f32 %1,%1,%1,%1\n"
                             "v_fma_f32 %2,%2,%2,%2\n"
                             "v_fma_f32 %3,%3,%3,%3\n"
                             "v_fma_f32 %0,%0,%0,%0\n"
                             "v_fma_f32 %1,%1,%1,%1\n"
                             "v_fma_f32 %2,%2,%2,%2\n"
                             "v_fma_f32 %3,%3,%3,%3"
                             : "+v"(j0), "+v"(j1), "+v"(j2), "+v"(j3));
            }
        }
        asm volatile("" ::: "memory");   // no code motion across the wait
        __syncthreads();
    }
}

extern "C" void kernel_launch(void* const* d_in, const int* in_sizes, int n_in,
                              void* d_out, int out_size, void* d_ws, size_t ws_size,
                              hipStream_t stream) {
    const float* x   = (const float*)d_in[0];
    const float* h0  = (const float*)d_in[1];
    const float* c0  = (const float*)d_in[2];
    const float* Wih = (const float*)d_in[3];
    const float* Whh = (const float*)d_in[4];
    const float* bih = (const float*)d_in[5];
    const float* bhh = (const float*)d_in[6];
    const float* mi  = (const float*)d_in[7];
    const float* mo  = (const float*)d_in[8];
    float* out = (float*)d_out;

    char* w = (char*)d_ws;
    _Float16* y0m = (_Float16*)w;                                  // 13,107,200 B
    _Float16* h0b = (_Float16*)(w + 13107200);                     //   131,072 B (2 bufs)
    _Float16* h1b = (_Float16*)(w + 13107200 + 131072);            //   131,072 B
    Bar*      bar = (Bar*)(w + 13107200 + 262144);

    hipLaunchKernelGGL(init_k, dim3(128), dim3(256), 0, stream, h0, h0b, h1b, bar);

    void* args[] = {(void*)&x, (void*)&c0, (void*)&Wih, (void*)&Whh,
                    (void*)&bih, (void*)&bhh, (void*)&mi, (void*)&mo,
                    (void*)&out, (void*)&y0m, (void*)&h0b, (void*)&h1b, (void*)&bar};
    hipLaunchCooperativeKernel((void*)lstm_main, dim3(NWG), dim3(NTHR),
                               args, 0, stream);
}

// Round 5
// 2147.828 us; speedup vs baseline: 1.1418x; 1.0136x over previous
//
#include <hip/hip_runtime.h>

#define T_STEPS 200
#define BATCH   32
#define HID     1024
#define NWG     256
#define NTHR    512

typedef _Float16 half8 __attribute__((ext_vector_type(8)));
typedef float    f32x4 __attribute__((ext_vector_type(4)));

struct Bar {
    unsigned cnt[2][8 * 32];   // [parity][group] arrival counters (one line each)
    unsigned gcnt[2 * 32];     // [parity] group-of-groups counter
    unsigned gen[8 * 32];      // 8 broadcast lines (released tick, monotonic)
};

// Coherent (agent-scope, cache-bypassing) 16B load/store from two relaxed 8B
// atomics. Used ONLY for cross-WG data (h ping-pong, y0m). No fences -> no
// buffer_inv / buffer_wbl2 anywhere.
__device__ __forceinline__ half8 ld_coh16(const _Float16* p) {
    union { unsigned long long u[2]; half8 h; } r;
    const unsigned long long* q = (const unsigned long long*)p;
    r.u[0] = __hip_atomic_load(q,     __ATOMIC_RELAXED, __HIP_MEMORY_SCOPE_AGENT);
    r.u[1] = __hip_atomic_load(q + 1, __ATOMIC_RELAXED, __HIP_MEMORY_SCOPE_AGENT);
    return r.h;
}
__device__ __forceinline__ void st_coh16(_Float16* p, half8 v) {
    union { half8 h; unsigned long long u[2]; } r; r.h = v;
    unsigned long long* q = (unsigned long long*)p;
    __hip_atomic_store(q,     r.u[0], __ATOMIC_RELAXED, __HIP_MEMORY_SCOPE_AGENT);
    __hip_atomic_store(q + 1, r.u[1], __ATOMIC_RELAXED, __HIP_MEMORY_SCOPE_AGENT);
}

__device__ __forceinline__ half8 cvt8(const float* p) {
    f32x4 lo = *(const f32x4*)p;
    f32x4 hi = *(const f32x4*)(p + 4);
    half8 a;
    a[0] = (_Float16)lo[0]; a[1] = (_Float16)lo[1];
    a[2] = (_Float16)lo[2]; a[3] = (_Float16)lo[3];
    a[4] = (_Float16)hi[0]; a[5] = (_Float16)hi[1];
    a[6] = (_Float16)hi[2]; a[7] = (_Float16)hi[3];
    return a;
}

__global__ void init_k(const float* __restrict__ h0,
                       _Float16* __restrict__ h0b, _Float16* __restrict__ h1b,
                       Bar* __restrict__ bar) {
    int i = blockIdx.x * blockDim.x + threadIdx.x;
    if (i < BATCH * HID) {
        h0b[i] = (_Float16)h0[i];                 // layer 0 initial h -> buf 0
        h1b[i] = (_Float16)h0[BATCH * HID + i];   // layer 1 initial h -> buf 0
    }
    if (blockIdx.x == 0) {
        if (threadIdx.x < 8) {
            bar->cnt[0][threadIdx.x * 32] = 0;
            bar->cnt[1][threadIdx.x * 32] = 0;
            bar->gen[threadIdx.x * 32]    = 0;
        }
        if (threadIdx.x < 2) bar->gcnt[threadIdx.x * 32] = 0;
    }
}

// 256 WGs x 512 threads. WGs 0-127: layer 0 (t = tick). WGs 128-255: layer 1
// (t = tick-1, wavefront pipeline). Weights persist in LDS (f16, XOR-swizzle).
// Cross-WG traffic (h ping-pong, y0m) via relaxed agent-scope atomics (LLC).
// Barrier = parity-RMW arrive + push release + busy spins (R4, proven).
// NEW: all pure-t inputs (x fragments, mi, mo) are register-prefetched under
// the barrier spin; out-stores moved to waves 4-7 (off wave-0's ack path).
__global__ __launch_bounds__(NTHR, 2) void lstm_main(
    const float* __restrict__ x, const float* __restrict__ c0,
    const float* __restrict__ Wih, const float* __restrict__ Whh,
    const float* __restrict__ bih, const float* __restrict__ bhh,
    const float* __restrict__ mi, const float* __restrict__ mo,
    float* __restrict__ out,
    _Float16* __restrict__ y0m, _Float16* __restrict__ h0b,
    _Float16* __restrict__ h1b, Bar* __restrict__ bar)
{
    __shared__ _Float16 W_s[32 * 2048];     // 128 KB
    __shared__ float scr[8][2][16][17];     // per-wave partial gate tiles (+pad)
    __shared__ float c_s[BATCH][8];         // persistent cell state (f32)
    __shared__ alignas(16) _Float16 st_h[BATCH][8];  // staged h for wave-0 stores
    __shared__ alignas(16) _Float16 st_y[BATCH][8];  // staged y0*mask (layer 0)
    __shared__ float st_o[BATCH][8];        // staged h for out-stores (layer 1)
    __shared__ unsigned rel_flag;           // intra-WG release (LDS)

    const int bid   = blockIdx.x;
    const int layer = bid >> 7;
    const int wgl   = bid & 127;
    const int tid   = threadIdx.x;

    if (tid == 0) rel_flag = 0;

    // ---- one-time: stage this WG's weight slice into LDS (f16, swizzled) ----
    const float* WihL = Wih + (size_t)layer * 4 * HID * HID;
    const float* WhhL = Whh + (size_t)layer * 4 * HID * HID;
    for (int idx = tid; idx < 32 * 2048; idx += NTHR) {
        int r = idx >> 11, k = idx & 2047;             // r: local gate-row, k: 0..2047
        int grow = (r >> 3) * HID + wgl * 8 + (r & 7); // global row in [4H]
        float v = (k < HID) ? WihL[(size_t)grow * HID + k]
                            : WhhL[(size_t)grow * HID + (k - HID)];
        W_s[idx ^ ((r & 7) << 3)] = (_Float16)v;       // XOR-swizzle (16B granules)
    }

    float bias0 = 0.f, bias1 = 0.f, bias2 = 0.f, bias3 = 0.f;
    int b_ = 0, col_ = 0, gcol = 0;
    if (tid < 256) {
        b_ = tid >> 3; col_ = tid & 7; gcol = wgl * 8 + col_;
        bias0 = bih[layer * 4096 + gcol]           + bhh[layer * 4096 + gcol];
        bias1 = bih[layer * 4096 + HID + gcol]     + bhh[layer * 4096 + HID + gcol];
        bias2 = bih[layer * 4096 + 2 * HID + gcol] + bhh[layer * 4096 + 2 * HID + gcol];
        bias3 = bih[layer * 4096 + 3 * HID + gcol] + bhh[layer * 4096 + 3 * HID + gcol];
        c_s[b_][col_] = c0[((size_t)layer * BATCH + b_) * HID + gcol];
    }
    // out-store threads (layer 1, waves 4-7): own (b2, c2)
    const int ot = tid - 256;
    const int b2 = (ot >= 0) ? (ot >> 3) : 0, c2 = (ot >= 0) ? (ot & 7) : 0;
    const int gcol2 = wgl * 8 + c2;
    __syncthreads();

    const int lane = tid & 63, wid = tid >> 6;
    const int m  = wid & 1;          // M-tile (batch 0-15 / 16-31)
    const int kq = wid >> 1;         // K quarter (512 each)
    const int row = lane & 15, bb = m * 16 + row, ko = (lane >> 4) * 8;
    const int grp = bid & 7;

    // ---- prefetched pure-t state for the upcoming tick ----
    half8 aF[16];
    float mi_reg = 0.f, mo_reg = 0.f;
    if (layer == 0) {
        if (kq < 2) {
            const float* xp = x + (size_t)bb * HID + kq * 512 + ko;   // t = 0
            #pragma unroll
            for (int kk = 0; kk < 16; ++kk) aF[kk] = cvt8(xp + kk * 32);
        }
        if (tid < 256) mi_reg = mi[(size_t)b_ * HID + gcol];          // t = 0
    }

    for (int tk = 0; tk <= T_STEPS; ++tk) {
        const bool active = (layer == 0) ? (tk < T_STEPS) : (tk >= 1);
        if (active) {
            const int t = (layer == 0) ? tk : tk - 1;
            // ---- barrier-dependent A fragments (h / y0m) ----
            if (layer == 0) {
                if (kq >= 2) {
                    const _Float16* hp = h0b + (tk & 1) * (BATCH * HID)
                                       + bb * HID + (kq - 2) * 512 + ko;
                    #pragma unroll
                    for (int kk = 0; kk < 16; ++kk) aF[kk] = ld_coh16(hp + kk * 32);
                }
            } else {
                if (kq < 2) {
                    const _Float16* yp = y0m + ((size_t)t * BATCH + bb) * HID + kq * 512 + ko;
                    #pragma unroll
                    for (int kk = 0; kk < 16; ++kk) aF[kk] = ld_coh16(yp + kk * 32);
                } else {
                    const _Float16* hp = h1b + (((tk + 1) & 1)) * (BATCH * HID)
                                       + bb * HID + (kq - 2) * 512 + ko;
                    #pragma unroll
                    for (int kk = 0; kk < 16; ++kk) aF[kk] = ld_coh16(hp + kk * 32);
                }
            }

            // ---- MFMA: D[batch 16][gaterow 16] x2 subtiles over K=512 ----
            f32x4 acc0 = {0.f, 0.f, 0.f, 0.f}, acc1 = {0.f, 0.f, 0.f, 0.f};
            #pragma unroll
            for (int kk = 0; kk < 16; ++kk) {
                const int k  = kq * 512 + kk * 32 + ko;
                const int r1 = 16 + row;
                const half8 bB0 = *(const half8*)&W_s[(row * 2048 + k) ^ ((row & 7) << 3)];
                const half8 bB1 = *(const half8*)&W_s[(r1 * 2048 + k) ^ ((r1 & 7) << 3)];
                acc0 = __builtin_amdgcn_mfma_f32_16x16x32_f16(aF[kk], bB0, acc0, 0, 0, 0);
                acc1 = __builtin_amdgcn_mfma_f32_16x16x32_f16(aF[kk], bB1, acc1, 0, 0, 0);
            }
            #pragma unroll
            for (int j = 0; j < 4; ++j) {
                scr[wid][0][(lane >> 4) * 4 + j][row] = acc0[j];
                scr[wid][1][(lane >> 4) * 4 + j][row] = acc1[j];
            }
            __syncthreads();

            // ---- activations: thread owns (batch b_, hidden col gcol) ----
            if (tid < 256) {
                const int m2 = b_ >> 4, rD = b_ & 15;
                float v0 = 0.f, v1 = 0.f, v2 = 0.f, v3 = 0.f;
                #pragma unroll
                for (int q = 0; q < 4; ++q) {
                    v0 += scr[q * 2 + m2][0][rD][col_];       // gate i
                    v1 += scr[q * 2 + m2][0][rD][8 + col_];   // gate f
                    v2 += scr[q * 2 + m2][1][rD][col_];       // gate g
                    v3 += scr[q * 2 + m2][1][rD][8 + col_];   // gate o
                }
                const float ig = 1.f / (1.f + __expf(-(v0 + bias0)));
                const float fg = 1.f / (1.f + __expf(-(v1 + bias1)));
                const float gg = tanhf(v2 + bias2);
                const float og = 1.f / (1.f + __expf(-(v3 + bias3)));
                const float cc = fg * c_s[b_][col_] + ig * gg;
                const float hh = og * tanhf(cc);
                c_s[b_][col_] = cc;

                st_h[b_][col_] = (_Float16)hh;
                if (layer == 0) {
                    st_y[b_][col_] = (_Float16)(hh * mi_reg);   // prefetched mask
                } else {
                    st_o[b_][col_] = hh;                        // out via waves 4-7
                }
                if (t == T_STEPS - 1) {
                    const size_t base = (size_t)T_STEPS * BATCH * HID;
                    out[base + ((size_t)layer * BATCH + b_) * HID + gcol] = hh;
                    out[base + (size_t)2 * BATCH * HID + ((size_t)layer * BATCH + b_) * HID + gcol] = cc;
                }
            }
            __syncthreads();

            // ---- wave 0 funnels ONLY the coherent cross-WG stores ----
            if (tid < BATCH) {
                _Float16* hwr = (layer == 0) ? (h0b + (((tk + 1) & 1)) * (BATCH * HID))
                                             : (h1b + ((tk & 1)) * (BATCH * HID));
                st_coh16(&hwr[tid * HID + wgl * 8], *(const half8*)st_h[tid]);
                if (layer == 0)
                    st_coh16(&y0m[((size_t)t * BATCH + tid) * HID + wgl * 8],
                             *(const half8*)st_y[tid]);
            }
            // ---- out-stores on waves 4-7 (never gate the barrier) ----
            if (layer == 1 && ot >= 0) {
                out[((size_t)t * BATCH + b2) * HID + gcol2] = st_o[b2][c2] * mo_reg;
            }
        }

        if (tk == T_STEPS) break;   // last tick: no barrier needed

        const unsigned tgt = (unsigned)(tk + 1);
        const int p = tk & 1;

        if (wid == 0) {
            // ---- arrive (lane 0): pipelined RMW aggregation, push release ----
            int pubi = 0;
            if (lane == 0) {
                asm volatile("s_waitcnt vmcnt(0)" ::: "memory");
                unsigned old = __hip_atomic_fetch_add(&bar->cnt[p][grp * 32], 1u,
                                   __ATOMIC_RELAXED, __HIP_MEMORY_SCOPE_AGENT);
                if (old == 31u) {
                    unsigned o2 = __hip_atomic_fetch_add(&bar->gcnt[p * 32], 1u,
                                       __ATOMIC_RELAXED, __HIP_MEMORY_SCOPE_AGENT);
                    pubi = (o2 == 7u) ? 1 : 0;
                }
            }
            pubi = __shfl(pubi, 0);
            if (pubi) {
                // lane-parallel publish + off-critical-path parity reset
                if (lane < 8)
                    __hip_atomic_store(&bar->gen[lane * 32], tgt,
                                       __ATOMIC_RELAXED, __HIP_MEMORY_SCOPE_AGENT);
                else if (lane < 16)
                    __hip_atomic_store(&bar->cnt[p][(lane - 8) * 32], 0u,
                                       __ATOMIC_RELAXED, __HIP_MEMORY_SCOPE_AGENT);
                else if (lane == 16)
                    __hip_atomic_store(&bar->gcnt[p * 32], 0u,
                                       __ATOMIC_RELAXED, __HIP_MEMORY_SCOPE_AGENT);
            }
            // ---- prefetch under the spin (wave 0 = layer's kq0/m0 wave) ----
            if (layer == 0 && kq < 2 && tk + 1 < T_STEPS) {
                const float* xp = x + ((size_t)(tk + 1) * BATCH + bb) * HID + kq * 512 + ko;
                #pragma unroll
                for (int kk = 0; kk < 16; ++kk) aF[kk] = cvt8(xp + kk * 32);
            }
            if (layer == 0 && tid < 256 && tk + 1 < T_STEPS)
                mi_reg = mi[((size_t)(tk + 1) * BATCH + b_) * HID + gcol];
            if (lane == 0) {
                if (!pubi) {
                    float j0 = 0.f, j1 = 0.f;
                    while (__hip_atomic_load(&bar->gen[grp * 32], __ATOMIC_RELAXED,
                                             __HIP_MEMORY_SCOPE_AGENT) < tgt) {
                        asm volatile("v_fma_f32 %0,%0,%0,%0\n"
                                     "v_fma_f32 %1,%1,%1,%1\n"
                                     "v_fma_f32 %0,%0,%0,%0\n"
                                     "v_fma_f32 %1,%1,%1,%1"
                                     : "+v"(j0), "+v"(j1));
                    }
                }
                *(volatile unsigned*)&rel_flag = tgt;
            }
        } else {
            // ---- waves 1-7: prefetch, then busy-wait on LDS flag ----
            if (layer == 0) {
                if (kq < 2 && tk + 1 < T_STEPS) {
                    const float* xp = x + ((size_t)(tk + 1) * BATCH + bb) * HID + kq * 512 + ko;
                    #pragma unroll
                    for (int kk = 0; kk < 16; ++kk) aF[kk] = cvt8(xp + kk * 32);
                }
                if (tid < 256 && tk + 1 < T_STEPS)
                    mi_reg = mi[((size_t)(tk + 1) * BATCH + b_) * HID + gcol];
            } else {
                if (ot >= 0 && tk < T_STEPS)
                    mo_reg = mo[((size_t)tk * BATCH + b2) * HID + gcol2];
            }
            float j0 = 0.f, j1 = 0.f, j2 = 0.f, j3 = 0.f;
            while (*(volatile unsigned*)&rel_flag < tgt) {
                asm volatile("v_fma_f32 %0,%0,%0,%0\n"
                             "v_fma_f32 %1,%1,%1,%1\n"
                             "v_fma_f32 %2,%2,%2,%2\n"
                             "v_fma_f32 %3,%3,%3,%3\n"
                             "v_fma_f32 %0,%0,%0,%0\n"
                             "v_fma_f32 %1,%1,%1,%1\n"
                             "v_fma_f32 %2,%2,%2,%2\n"
                             "v_fma_f32 %3,%3,%3,%3"
                             : "+v"(j0), "+v"(j1), "+v"(j2), "+v"(j3));
            }
        }
        asm volatile("" ::: "memory");   // no code motion across the wait
        __syncthreads();
    }
}

extern "C" void kernel_launch(void* const* d_in, const int* in_sizes, int n_in,
                              void* d_out, int out_size, void* d_ws, size_t ws_size,
                              hipStream_t stream) {
    const float* x   = (const float*)d_in[0];
    const float* h0  = (const float*)d_in[1];
    const float* c0  = (const float*)d_in[2];
    const float* Wih = (const float*)d_in[3];
    const float* Whh = (const float*)d_in[4];
    const float* bih = (const float*)d_in[5];
    const float* bhh = (const float*)d_in[6];
    const float* mi  = (const float*)d_in[7];
    const float* mo  = (const float*)d_in[8];
    float* out = (float*)d_out;

    char* w = (char*)d_ws;
    _Float16* y0m = (_Float16*)w;                                  // 13,107,200 B
    _Float16* h0b = (_Float16*)(w + 13107200);                     //   131,072 B (2 bufs)
    _Float16* h1b = (_Float16*)(w + 13107200 + 131072);            //   131,072 B
    Bar*      bar = (Bar*)(w + 13107200 + 262144);

    hipLaunchKernelGGL(init_k, dim3(128), dim3(256), 0, stream, h0, h0b, h1b, bar);

    void* args[] = {(void*)&x, (void*)&c0, (void*)&Wih, (void*)&Whh,
                    (void*)&bih, (void*)&bhh, (void*)&mi, (void*)&mo,
                    (void*)&out, (void*)&y0m, (void*)&h0b, (void*)&h1b, (void*)&bar};
    hipLaunchCooperativeKernel((void*)lstm_main, dim3(NWG), dim3(NTHR),
                               args, 0, stream);
}